// Round 7
// baseline (319.735 us; speedup 1.0000x reference)
//
#include <hip/hip_runtime.h>

#define N_NODES 50000
#define N_EDGES 800000
#define NEG_SLOPE 0.2f

__device__ __forceinline__ float leaky(float x) { return x >= 0.f ? x : NEG_SLOPE * x; }

// ---------------------------------------------------------------------------
// Register-tiled GEMM + attention scores: h = x@W (W: [K,64] row-major),
// s_src = h@a_src, s_dst = h@a_dst.  64x64 tile, BK=32, 4x4 per thread.
// ---------------------------------------------------------------------------
template <int K>
__global__ __launch_bounds__(256) void gat_gemm_kernel(
    const float* __restrict__ x, const float* __restrict__ W,
    const float* __restrict__ a_src, const float* __restrict__ a_dst,
    float* __restrict__ h, float* __restrict__ s_src, float* __restrict__ s_dst,
    int n)
{
    constexpr int BK = 32;
    __shared__ float Wl[BK][64];
    __shared__ float xt[BK][68];
    __shared__ float asl[64], adl[64];

    int tid = threadIdx.x;
    if (tid < 64) { asl[tid] = a_src[tid]; adl[tid] = a_dst[tid]; }
    int tx = tid & 15, ty = tid >> 4;
    int row0 = blockIdx.x * 64;

    float acc[4][4] = {};

    for (int k0 = 0; k0 < K; k0 += BK) {
        __syncthreads();
        {
            const float4* Wg = (const float4*)&W[(size_t)k0 * 64];
            float4* Ws = (float4*)&Wl[0][0];
            Ws[tid]       = Wg[tid];
            Ws[tid + 256] = Wg[tid + 256];
        }
        #pragma unroll
        for (int it = 0; it < 2; ++it) {
            int idx = tid + it * 256;
            int r = idx >> 3, kq = idx & 7;
            int grow = row0 + r;
            float4 v = (grow < n) ? *(const float4*)&x[(size_t)grow * K + k0 + kq * 4]
                                  : make_float4(0.f, 0.f, 0.f, 0.f);
            xt[kq * 4 + 0][r] = v.x;
            xt[kq * 4 + 1][r] = v.y;
            xt[kq * 4 + 2][r] = v.z;
            xt[kq * 4 + 3][r] = v.w;
        }
        __syncthreads();

        #pragma unroll
        for (int kk = 0; kk < BK; ++kk) {
            float4 wv = *(const float4*)&Wl[kk][tx * 4];
            float4 xv = *(const float4*)&xt[kk][ty * 4];
            acc[0][0] += xv.x * wv.x; acc[0][1] += xv.x * wv.y; acc[0][2] += xv.x * wv.z; acc[0][3] += xv.x * wv.w;
            acc[1][0] += xv.y * wv.x; acc[1][1] += xv.y * wv.y; acc[1][2] += xv.y * wv.z; acc[1][3] += xv.y * wv.w;
            acc[2][0] += xv.z * wv.x; acc[2][1] += xv.z * wv.y; acc[2][2] += xv.z * wv.z; acc[2][3] += xv.z * wv.w;
            acc[3][0] += xv.w * wv.x; acc[3][1] += xv.w * wv.y; acc[3][2] += xv.w * wv.z; acc[3][3] += xv.w * wv.w;
        }
    }

    #pragma unroll
    for (int i = 0; i < 4; ++i) {
        int grow = row0 + ty * 4 + i;
        if (grow < n) {
            float4 o = make_float4(acc[i][0], acc[i][1], acc[i][2], acc[i][3]);
            *(float4*)&h[(size_t)grow * 64 + tx * 4] = o;
        }
        float s1 = acc[i][0] * asl[tx*4+0] + acc[i][1] * asl[tx*4+1]
                 + acc[i][2] * asl[tx*4+2] + acc[i][3] * asl[tx*4+3];
        float s2 = acc[i][0] * adl[tx*4+0] + acc[i][1] * adl[tx*4+1]
                 + acc[i][2] * adl[tx*4+2] + acc[i][3] * adl[tx*4+3];
        #pragma unroll
        for (int m = 1; m < 16; m <<= 1) {
            s1 += __shfl_xor(s1, m, 64);
            s2 += __shfl_xor(s2, m, 64);
        }
        if (tx == 0 && grow < n) { s_src[grow] = s1; s_dst[grow] = s2; }
    }
}

// ---------------------------------------------------------------------------
// CSR build: count(+rank) -> scan1 -> scanApply -> atomic-free scatter
// ---------------------------------------------------------------------------
__global__ __launch_bounds__(256) void count_rank_kernel(
    const int* __restrict__ dst, int* __restrict__ counts, int* __restrict__ rank)
{
    int e = blockIdx.x * 256 + threadIdx.x;
    if (e >= N_EDGES) return;
    rank[e] = atomicAdd(&counts[dst[e]], 1);
}

__global__ __launch_bounds__(256) void scan1_kernel(
    const int* __restrict__ counts, int* __restrict__ row_off,
    int* __restrict__ bsum, int n)
{
    __shared__ int tmp[256];
    int tid = threadIdx.x;
    int i = blockIdx.x * 256 + tid;
    int v = (i < n) ? counts[i] : 0;
    tmp[tid] = v; __syncthreads();
    for (int off = 1; off < 256; off <<= 1) {
        int add = (tid >= off) ? tmp[tid - off] : 0;
        __syncthreads();
        tmp[tid] += add;
        __syncthreads();
    }
    if (i < n) row_off[i] = tmp[tid] - v;
    if (tid == 255) bsum[blockIdx.x] = tmp[255];
}

// each block redundantly scans the <=256 block sums in LDS, then applies its
// own prefix (merges old scan2+scan3, removes a serialized tiny launch)
__global__ __launch_bounds__(256) void scan_apply_kernel(
    int* __restrict__ row_off, const int* __restrict__ bsum, int n, int nb)
{
    __shared__ int tmp[256];
    int tid = threadIdx.x;
    int v = (tid < nb) ? bsum[tid] : 0;
    tmp[tid] = v; __syncthreads();
    for (int off = 1; off < 256; off <<= 1) {
        int add = (tid >= off) ? tmp[tid - off] : 0;
        __syncthreads();
        tmp[tid] += add;
        __syncthreads();
    }
    int prefix = (blockIdx.x == 0) ? 0 : tmp[blockIdx.x - 1];  // inclusive sum of prior blocks
    int i = blockIdx.x * 256 + tid;
    if (i < n) row_off[i] += prefix;
    if (i == 0) row_off[n] = N_EDGES;
}

__global__ __launch_bounds__(256) void scatter_kernel(
    const int* __restrict__ src, const int* __restrict__ dst,
    const int* __restrict__ row_off, const int* __restrict__ rank,
    int* __restrict__ csr_src)
{
    int e = blockIdx.x * 256 + threadIdx.x;
    if (e >= N_EDGES) return;
    csr_src[row_off[dst[e]] + rank[e]] = src[e];
}

// ---------------------------------------------------------------------------
// Feature-sliced fused per-node attention kernel.
// slice = blockIdx & 3 (16 dims); blockIdx%8 -> XCD, so each XCD's L2 only
// caches a 50000x16 slice of h (3.2 MB, L2-resident). One wave per node;
// lanes = 4 edges x 16 dims per gather batch; quarter results reduced at end.
// ---------------------------------------------------------------------------
template <bool RELU>
__global__ __launch_bounds__(256) void gat_node_kernel(
    const int* __restrict__ row_off, const int* __restrict__ csr_src,
    const float* __restrict__ s_src, const float* __restrict__ s_dst,
    const float* __restrict__ h, const float* __restrict__ b,
    float* __restrict__ out, int n)
{
    int slice = blockIdx.x & 3;
    int row = (blockIdx.x >> 2) * 4 + (threadIdx.x >> 6);
    int lane = threadIdx.x & 63;
    if (row >= n) return;
    int esub = lane >> 4;          // edge sub-group 0..3
    int sl   = lane & 15;          // dim within slice
    int dbase = slice * 16 + sl;   // feature dim this lane owns

    int beg = row_off[row], end = row_off[row + 1];
    int deg = end - beg;
    float sd = s_dst[row];
    float self_logit = leaky(s_src[row] + sd);
    float hself = h[(size_t)row * 64 + dbase];   // one 64B line per wave

    // pass A: per-lane edge (first 64) + strided tail -> wave max
    int   mysrc   = 0;
    float mylogit = -INFINITY;     // -> w64 = 0 for invalid lanes
    if (lane < deg) {
        mysrc = csr_src[beg + lane];
        mylogit = leaky(s_src[mysrc] + sd);
    }
    float mx = fmaxf(self_logit, mylogit);
    for (int e = beg + 64 + lane; e < end; e += 64) {
        int s = csr_src[e];
        mx = fmaxf(mx, leaky(s_src[s] + sd));
    }
    #pragma unroll
    for (int off = 32; off; off >>= 1)
        mx = fmaxf(mx, __shfl_xor(mx, off, 64));

    float w64 = __expf(mylogit - mx);
    float den = w64;
    #pragma unroll
    for (int off = 32; off; off >>= 1)
        den += __shfl_xor(den, off, 64);
    float wself = __expf(self_logit - mx);
    den += wself;

    // self contribution only in quarter 0 (final reduce sums quarters)
    float acc = (esub == 0) ? wself * hself : 0.f;

    // pass B: 4 edges x 16 dims per iteration; unroll 4 -> 16 edge-rows in flight
    int d0 = deg < 64 ? deg : 64;
    int nb = (d0 + 15) & ~15;
    #pragma unroll 4
    for (int i = 0; i < nb; i += 4) {
        int idx = i + esub;                    // same within each 16-lane quarter
        int   s = __shfl(mysrc, idx, 64);      // ds_bpermute, 1 per 4 edges
        float w = __shfl(w64, idx, 64);
        acc += w * h[(size_t)s * 64 + dbase];  // idx >= deg: w = 0, row 0 (hot)
    }
    // rare tail: deg > 64 (w uniform across lanes; acc gated to quarter 0)
    for (int e = beg + 64; e < end; ++e) {
        int s = csr_src[e];
        float w = __expf(leaky(s_src[s] + sd) - mx);
        den += w;
        if (esub == 0) acc += w * h[(size_t)s * 64 + dbase];
    }

    // sum the 4 quarters (lanes with equal sl share a dim)
    acc += __shfl_xor(acc, 16, 64);
    acc += __shfl_xor(acc, 32, 64);

    if (esub == 0) {
        float v = acc / den + b[dbase];
        if (RELU) v = fmaxf(v, 0.f);
        out[(size_t)row * 64 + dbase] = v;
    }
}

// ---------------------------------------------------------------------------
extern "C" void kernel_launch(void* const* d_in, const int* in_sizes, int n_in,
                              void* d_out, int out_size, void* d_ws, size_t ws_size,
                              hipStream_t stream) {
    const float* x   = (const float*)d_in[0];
    const int*   ei  = (const int*)d_in[1];
    const float* W1  = (const float*)d_in[2];
    const float* a1s = (const float*)d_in[3];
    const float* a1d = (const float*)d_in[4];
    const float* b1  = (const float*)d_in[5];
    const float* W2  = (const float*)d_in[6];
    const float* a2s = (const float*)d_in[7];
    const float* a2d = (const float*)d_in[8];
    const float* b2  = (const float*)d_in[9];
    float* out = (float*)d_out;

    const int* src = ei;
    const int* dst = ei + N_EDGES;

    char* p = (char*)d_ws;
    float* h    = (float*)p;            p += (size_t)N_NODES * 64 * 4;
    float* ssrc = (float*)p;            p += (size_t)N_NODES * 4;
    float* sdst = (float*)p;            p += (size_t)N_NODES * 4;
    int* row_off = (int*)p;             p += (size_t)(N_NODES + 1) * 4;
    int* counts  = (int*)p;             p += (size_t)N_NODES * 4;
    int* bsum    = (int*)p;             p += 256 * 4;
    int* csr_src = (int*)p;             p += (size_t)N_EDGES * 4;

    int* rank = (int*)h;   // h (12.8 MB) is dead until gemm1; rank needs 3.2 MB

    dim3 blk(256);
    int gemm_blocks   = (N_NODES + 63) / 64;
    int node_blocks   = ((N_NODES + 3) / 4) * 4;   // x4 feature slices
    int edge_blocks_t = (N_EDGES + 255) / 256;
    int scan_blocks   = (N_NODES + 255) / 256;

    // ---- CSR build (atomic-free scatter via precomputed ranks) ----
    hipMemsetAsync(counts, 0, (size_t)N_NODES * 4, stream);
    count_rank_kernel<<<edge_blocks_t, blk, 0, stream>>>(dst, counts, rank);
    scan1_kernel<<<scan_blocks, blk, 0, stream>>>(counts, row_off, bsum, N_NODES);
    scan_apply_kernel<<<scan_blocks, blk, 0, stream>>>(row_off, bsum, N_NODES, scan_blocks);
    scatter_kernel<<<edge_blocks_t, blk, 0, stream>>>(src, dst, row_off, rank, csr_src);

    // ---- layer 1 ----
    gat_gemm_kernel<128><<<gemm_blocks, blk, 0, stream>>>(x, W1, a1s, a1d, h, ssrc, sdst, N_NODES);
    gat_node_kernel<true><<<node_blocks, blk, 0, stream>>>(row_off, csr_src, ssrc, sdst, h, b1, out, N_NODES);

    // ---- layer 2 ----
    gat_gemm_kernel<64><<<gemm_blocks, blk, 0, stream>>>(out, W2, a2s, a2d, h, ssrc, sdst, N_NODES);
    gat_node_kernel<false><<<node_blocks, blk, 0, stream>>>(row_off, csr_src, ssrc, sdst, h, b2, out, N_NODES);
}

// Round 8
// 174.756 us; speedup vs baseline: 1.8296x; 1.8296x over previous
//
#include <hip/hip_runtime.h>

#define N_NODES 50000
#define N_EDGES 800000
#define NEG_SLOPE 0.2f

__device__ __forceinline__ float leaky(float x) { return x >= 0.f ? x : NEG_SLOPE * x; }
__device__ __forceinline__ float readlane_f(float v, int i) {
    return __uint_as_float(__builtin_amdgcn_readlane(__float_as_uint(v), i));
}
// order-preserving float<->uint mapping for atomicMax on mixed-sign floats
__device__ __forceinline__ unsigned enc_f(float f) {
    unsigned u = __float_as_uint(f);
    return (int)u < 0 ? ~u : (u | 0x80000000u);
}
__device__ __forceinline__ float dec_f(unsigned e) {
    return __uint_as_float((int)e < 0 ? (e & 0x7FFFFFFFu) : ~e);
}

// ---------------------------------------------------------------------------
// Register-tiled GEMM + attention scores: h = x@W (W: [K,64] row-major),
// s_src = h@a_src, s_dst = h@a_dst.  64x64 tile, BK=32, 4x4 per thread.
// Epilogue also accumulates gmax = max(s_src) (ordered-uint atomicMax).
// ---------------------------------------------------------------------------
template <int K>
__global__ __launch_bounds__(256) void gat_gemm_kernel(
    const float* __restrict__ x, const float* __restrict__ W,
    const float* __restrict__ a_src, const float* __restrict__ a_dst,
    float* __restrict__ h, float* __restrict__ s_src, float* __restrict__ s_dst,
    unsigned* __restrict__ gmax_enc, int n)
{
    constexpr int BK = 32;
    __shared__ float Wl[BK][64];
    __shared__ float xt[BK][68];
    __shared__ float asl[64], adl[64];
    __shared__ float wm[4];

    int tid = threadIdx.x;
    if (tid < 64) { asl[tid] = a_src[tid]; adl[tid] = a_dst[tid]; }
    int tx = tid & 15, ty = tid >> 4;
    int row0 = blockIdx.x * 64;

    float acc[4][4] = {};

    for (int k0 = 0; k0 < K; k0 += BK) {
        __syncthreads();
        {
            const float4* Wg = (const float4*)&W[(size_t)k0 * 64];
            float4* Ws = (float4*)&Wl[0][0];
            Ws[tid]       = Wg[tid];
            Ws[tid + 256] = Wg[tid + 256];
        }
        #pragma unroll
        for (int it = 0; it < 2; ++it) {
            int idx = tid + it * 256;
            int r = idx >> 3, kq = idx & 7;
            int grow = row0 + r;
            float4 v = (grow < n) ? *(const float4*)&x[(size_t)grow * K + k0 + kq * 4]
                                  : make_float4(0.f, 0.f, 0.f, 0.f);
            xt[kq * 4 + 0][r] = v.x;
            xt[kq * 4 + 1][r] = v.y;
            xt[kq * 4 + 2][r] = v.z;
            xt[kq * 4 + 3][r] = v.w;
        }
        __syncthreads();

        #pragma unroll
        for (int kk = 0; kk < BK; ++kk) {
            float4 wv = *(const float4*)&Wl[kk][tx * 4];
            float4 xv = *(const float4*)&xt[kk][ty * 4];
            acc[0][0] += xv.x * wv.x; acc[0][1] += xv.x * wv.y; acc[0][2] += xv.x * wv.z; acc[0][3] += xv.x * wv.w;
            acc[1][0] += xv.y * wv.x; acc[1][1] += xv.y * wv.y; acc[1][2] += xv.y * wv.z; acc[1][3] += xv.y * wv.w;
            acc[2][0] += xv.z * wv.x; acc[2][1] += xv.z * wv.y; acc[2][2] += xv.z * wv.z; acc[2][3] += xv.z * wv.w;
            acc[3][0] += xv.w * wv.x; acc[3][1] += xv.w * wv.y; acc[3][2] += xv.w * wv.z; acc[3][3] += xv.w * wv.w;
        }
    }

    float wmax = -INFINITY;
    #pragma unroll
    for (int i = 0; i < 4; ++i) {
        int grow = row0 + ty * 4 + i;
        if (grow < n) {
            float4 o = make_float4(acc[i][0], acc[i][1], acc[i][2], acc[i][3]);
            *(float4*)&h[(size_t)grow * 64 + tx * 4] = o;
        }
        float s1 = acc[i][0] * asl[tx*4+0] + acc[i][1] * asl[tx*4+1]
                 + acc[i][2] * asl[tx*4+2] + acc[i][3] * asl[tx*4+3];
        float s2 = acc[i][0] * adl[tx*4+0] + acc[i][1] * adl[tx*4+1]
                 + acc[i][2] * adl[tx*4+2] + acc[i][3] * adl[tx*4+3];
        #pragma unroll
        for (int m = 1; m < 16; m <<= 1) {
            s1 += __shfl_xor(s1, m, 64);
            s2 += __shfl_xor(s2, m, 64);
        }
        if (grow < n) wmax = fmaxf(wmax, s1);          // s1 uniform across tx group
        if (tx == 0 && grow < n) { s_src[grow] = s1; s_dst[grow] = s2; }
    }
    // block max of s_src -> one atomic per block
    wmax = fmaxf(wmax, __shfl_xor(wmax, 16, 64));
    wmax = fmaxf(wmax, __shfl_xor(wmax, 32, 64));
    if ((tid & 63) == 0) wm[tid >> 6] = wmax;
    __syncthreads();
    if (tid == 0) {
        float bm = fmaxf(fmaxf(wm[0], wm[1]), fmaxf(wm[2], wm[3]));
        atomicMax(gmax_enc, enc_f(bm));
    }
}

// ---------------------------------------------------------------------------
// CSR build: count(+rank) -> scan1 -> scanApply -> atomic-free scatter
// ---------------------------------------------------------------------------
__global__ __launch_bounds__(256) void count_rank_kernel(
    const int* __restrict__ dst, int* __restrict__ counts, int* __restrict__ rank)
{
    int e = blockIdx.x * 256 + threadIdx.x;
    if (e >= N_EDGES) return;
    rank[e] = atomicAdd(&counts[dst[e]], 1);
}

__global__ __launch_bounds__(256) void scan1_kernel(
    const int* __restrict__ counts, int* __restrict__ row_off,
    int* __restrict__ bsum, int n)
{
    __shared__ int tmp[256];
    int tid = threadIdx.x;
    int i = blockIdx.x * 256 + tid;
    int v = (i < n) ? counts[i] : 0;
    tmp[tid] = v; __syncthreads();
    for (int off = 1; off < 256; off <<= 1) {
        int add = (tid >= off) ? tmp[tid - off] : 0;
        __syncthreads();
        tmp[tid] += add;
        __syncthreads();
    }
    if (i < n) row_off[i] = tmp[tid] - v;
    if (tid == 255) bsum[blockIdx.x] = tmp[255];
}

__global__ __launch_bounds__(256) void scan_apply_kernel(
    int* __restrict__ row_off, const int* __restrict__ bsum, int n, int nb)
{
    __shared__ int tmp[256];
    int tid = threadIdx.x;
    int v = (tid < nb) ? bsum[tid] : 0;
    tmp[tid] = v; __syncthreads();
    for (int off = 1; off < 256; off <<= 1) {
        int add = (tid >= off) ? tmp[tid - off] : 0;
        __syncthreads();
        tmp[tid] += add;
        __syncthreads();
    }
    int prefix = (blockIdx.x == 0) ? 0 : tmp[blockIdx.x - 1];
    int i = blockIdx.x * 256 + tid;
    if (i < n) row_off[i] += prefix;
    if (i == 0) row_off[n] = N_EDGES;
}

__global__ __launch_bounds__(256) void scatter_kernel(
    const int* __restrict__ src, const int* __restrict__ dst,
    const int* __restrict__ row_off, const int* __restrict__ rank,
    int* __restrict__ csr_src)
{
    int e = blockIdx.x * 256 + threadIdx.x;
    if (e >= N_EDGES) return;
    csr_src[row_off[dst[e]] + rank[e]] = src[e];
}

// ---------------------------------------------------------------------------
// Fused per-node attention kernel. One wave per dst node.
// m = leaky(gmax + sd) is a wave-uniform logit upper bound (cancels exactly
// in softmax) -> no max pass, and h-row gathers depend ONLY on csr_src:
// critical path = csr_src load -> 32-salvo h loads -> FMAs. The s-gather,
// exp and den-reduce all hide under the h loads.
// ---------------------------------------------------------------------------
template <bool RELU>
__global__ __launch_bounds__(256) void gat_node_kernel(
    const int* __restrict__ row_off, const int* __restrict__ csr_src,
    const float* __restrict__ s_src, const float* __restrict__ s_dst,
    const float* __restrict__ h, const float* __restrict__ b,
    const unsigned* __restrict__ gmax_enc, float* __restrict__ out, int n)
{
    int row = blockIdx.x * 4 + (threadIdx.x >> 6);
    int lane = threadIdx.x & 63;
    if (row >= n) return;

    int beg = row_off[row], end = row_off[row + 1];
    int deg = end - beg;
    float sd = s_dst[row];
    float m = leaky(dec_f(*gmax_enc) + sd);     // >= every incoming logit
    float s_self = s_src[row];
    float hself = h[(size_t)row * 64 + lane];
    float wself = __expf(leaky(s_self + sd) - m);

    if (deg <= 32) {                            // ~all nodes (Poisson lambda=16)
        int mysrc = row;                        // filler: hot self row, w=0
        if (lane < deg) mysrc = csr_src[beg + lane];
        float my_s = s_src[mysrc];
        float hv[32];
        #pragma unroll
        for (int j = 0; j < 32; ++j) {
            int s = __builtin_amdgcn_readlane(mysrc, j);
            hv[j] = h[(size_t)s * 64 + lane];
        }
        float mylogit = (lane < deg) ? leaky(my_s + sd) : -INFINITY;
        float w64 = __expf(mylogit - m);
        float den = w64;
        #pragma unroll
        for (int off = 32; off; off >>= 1)
            den += __shfl_xor(den, off, 64);
        den += wself;

        float acc = wself * hself;
        #pragma unroll
        for (int j = 0; j < 32; ++j)
            acc += readlane_f(w64, j) * hv[j];

        float v = acc / den + b[lane];
        if (RELU) v = fmaxf(v, 0.f);
        out[(size_t)row * 64 + lane] = v;
        return;
    }

    // generic path: deg > 32 (rare)
    int   mysrc   = row;
    float mylogit = -INFINITY;
    if (lane < deg) {
        mysrc = csr_src[beg + lane];
        mylogit = leaky(s_src[mysrc] + sd);
    }
    float w64 = __expf(mylogit - m);
    float den = w64;
    #pragma unroll
    for (int off = 32; off; off >>= 1)
        den += __shfl_xor(den, off, 64);
    den += wself;

    float acc = wself * hself;
    int d0 = deg < 64 ? deg : 64;
    int nb = (d0 + 15) & ~15;
    for (int i = 0; i < nb; i += 16) {
        float hv[16];
        #pragma unroll
        for (int j = 0; j < 16; ++j) {
            int s = __builtin_amdgcn_readlane(mysrc, i + j);
            hv[j] = h[(size_t)s * 64 + lane];
        }
        #pragma unroll
        for (int j = 0; j < 16; ++j)
            acc += readlane_f(w64, i + j) * hv[j];
    }
    for (int e = beg + 64; e < end; ++e) {      // deg > 64 tail
        int s = csr_src[e];
        float w = __expf(leaky(s_src[s] + sd) - m);
        den += w;
        acc += w * h[(size_t)s * 64 + lane];
    }

    float v = acc / den + b[lane];
    if (RELU) v = fmaxf(v, 0.f);
    out[(size_t)row * 64 + lane] = v;
}

// ---------------------------------------------------------------------------
extern "C" void kernel_launch(void* const* d_in, const int* in_sizes, int n_in,
                              void* d_out, int out_size, void* d_ws, size_t ws_size,
                              hipStream_t stream) {
    const float* x   = (const float*)d_in[0];
    const int*   ei  = (const int*)d_in[1];
    const float* W1  = (const float*)d_in[2];
    const float* a1s = (const float*)d_in[3];
    const float* a1d = (const float*)d_in[4];
    const float* b1  = (const float*)d_in[5];
    const float* W2  = (const float*)d_in[6];
    const float* a2s = (const float*)d_in[7];
    const float* a2d = (const float*)d_in[8];
    const float* b2  = (const float*)d_in[9];
    float* out = (float*)d_out;

    const int* src = ei;
    const int* dst = ei + N_EDGES;

    char* p = (char*)d_ws;
    float* h    = (float*)p;            p += (size_t)N_NODES * 64 * 4;
    float* ssrc = (float*)p;            p += (size_t)N_NODES * 4;
    float* sdst = (float*)p;            p += (size_t)N_NODES * 4;
    int* row_off = (int*)p;             p += (size_t)(N_NODES + 1) * 4;
    int* bsum    = (int*)p;             p += 256 * 4;
    unsigned* gmaxu = (unsigned*)p;     p += 2 * 4;          // [gmax1, gmax2]
    int* counts  = (int*)p;             p += (size_t)N_NODES * 4;   // contiguous after gmaxu
    int* csr_src = (int*)p;             p += (size_t)N_EDGES * 4;

    int* rank = (int*)h;   // h (12.8 MB) is dead until gemm1; rank needs 3.2 MB

    dim3 blk(256);
    int gemm_blocks   = (N_NODES + 63) / 64;
    int node_blocks   = (N_NODES + 3) / 4;
    int edge_blocks_t = (N_EDGES + 255) / 256;
    int scan_blocks   = (N_NODES + 255) / 256;

    // ---- CSR build (atomic-free scatter via precomputed ranks) ----
    hipMemsetAsync(gmaxu, 0, 8 + (size_t)N_NODES * 4, stream);  // gmax slots + counts
    count_rank_kernel<<<edge_blocks_t, blk, 0, stream>>>(dst, counts, rank);
    scan1_kernel<<<scan_blocks, blk, 0, stream>>>(counts, row_off, bsum, N_NODES);
    scan_apply_kernel<<<scan_blocks, blk, 0, stream>>>(row_off, bsum, N_NODES, scan_blocks);
    scatter_kernel<<<edge_blocks_t, blk, 0, stream>>>(src, dst, row_off, rank, csr_src);

    // ---- layer 1 ----
    gat_gemm_kernel<128><<<gemm_blocks, blk, 0, stream>>>(x, W1, a1s, a1d, h, ssrc, sdst, gmaxu + 0, N_NODES);
    gat_node_kernel<true><<<node_blocks, blk, 0, stream>>>(row_off, csr_src, ssrc, sdst, h, b1, gmaxu + 0, out, N_NODES);

    // ---- layer 2 ----
    gat_gemm_kernel<64><<<gemm_blocks, blk, 0, stream>>>(out, W2, a2s, a2d, h, ssrc, sdst, gmaxu + 1, N_NODES);
    gat_node_kernel<false><<<node_blocks, blk, 0, stream>>>(row_off, csr_src, ssrc, sdst, h, b2, gmaxu + 1, out, N_NODES);
}

// Round 9
// 165.066 us; speedup vs baseline: 1.9370x; 1.0587x over previous
//
#include <hip/hip_runtime.h>
#include <hip/hip_fp16.h>

#define N_NODES 50000
#define N_EDGES 800000
#define NEG_SLOPE 0.2f

__device__ __forceinline__ float leaky(float x) { return x >= 0.f ? x : NEG_SLOPE * x; }
__device__ __forceinline__ float readlane_f(float v, int i) {
    return __uint_as_float(__builtin_amdgcn_readlane(__float_as_uint(v), i));
}
// order-preserving float<->uint mapping for atomicMax on mixed-sign floats
__device__ __forceinline__ unsigned enc_f(float f) {
    unsigned u = __float_as_uint(f);
    return (int)u < 0 ? ~u : (u | 0x80000000u);
}
__device__ __forceinline__ float dec_f(unsigned e) {
    return __uint_as_float((int)e < 0 ? (e & 0x7FFFFFFFu) : ~e);
}

// ---------------------------------------------------------------------------
// Register-tiled GEMM + attention scores: h(fp16) = x@W (W: [K,64] row-major),
// s_src = h@a_src, s_dst = h@a_dst (f32). 64x64 tile, BK=32, 4x4 per thread.
// Epilogue also accumulates gmax = max(s_src) (ordered-uint atomicMax).
// h stored fp16: halves gather bytes in the node kernel (the L3 service wall).
// ---------------------------------------------------------------------------
template <int K>
__global__ __launch_bounds__(256) void gat_gemm_kernel(
    const float* __restrict__ x, const float* __restrict__ W,
    const float* __restrict__ a_src, const float* __restrict__ a_dst,
    __half* __restrict__ h, float* __restrict__ s_src, float* __restrict__ s_dst,
    unsigned* __restrict__ gmax_enc, int n)
{
    constexpr int BK = 32;
    __shared__ float Wl[BK][64];
    __shared__ float xt[BK][68];
    __shared__ float asl[64], adl[64];
    __shared__ float wm[4];

    int tid = threadIdx.x;
    if (tid < 64) { asl[tid] = a_src[tid]; adl[tid] = a_dst[tid]; }
    int tx = tid & 15, ty = tid >> 4;
    int row0 = blockIdx.x * 64;

    float acc[4][4] = {};

    for (int k0 = 0; k0 < K; k0 += BK) {
        __syncthreads();
        {
            const float4* Wg = (const float4*)&W[(size_t)k0 * 64];
            float4* Ws = (float4*)&Wl[0][0];
            Ws[tid]       = Wg[tid];
            Ws[tid + 256] = Wg[tid + 256];
        }
        #pragma unroll
        for (int it = 0; it < 2; ++it) {
            int idx = tid + it * 256;
            int r = idx >> 3, kq = idx & 7;
            int grow = row0 + r;
            float4 v = (grow < n) ? *(const float4*)&x[(size_t)grow * K + k0 + kq * 4]
                                  : make_float4(0.f, 0.f, 0.f, 0.f);
            xt[kq * 4 + 0][r] = v.x;
            xt[kq * 4 + 1][r] = v.y;
            xt[kq * 4 + 2][r] = v.z;
            xt[kq * 4 + 3][r] = v.w;
        }
        __syncthreads();

        #pragma unroll
        for (int kk = 0; kk < BK; ++kk) {
            float4 wv = *(const float4*)&Wl[kk][tx * 4];
            float4 xv = *(const float4*)&xt[kk][ty * 4];
            acc[0][0] += xv.x * wv.x; acc[0][1] += xv.x * wv.y; acc[0][2] += xv.x * wv.z; acc[0][3] += xv.x * wv.w;
            acc[1][0] += xv.y * wv.x; acc[1][1] += xv.y * wv.y; acc[1][2] += xv.y * wv.z; acc[1][3] += xv.y * wv.w;
            acc[2][0] += xv.z * wv.x; acc[2][1] += xv.z * wv.y; acc[2][2] += xv.z * wv.z; acc[2][3] += xv.z * wv.w;
            acc[3][0] += xv.w * wv.x; acc[3][1] += xv.w * wv.y; acc[3][2] += xv.w * wv.z; acc[3][3] += xv.w * wv.w;
        }
    }

    float wmax = -INFINITY;
    #pragma unroll
    for (int i = 0; i < 4; ++i) {
        int grow = row0 + ty * 4 + i;
        if (grow < n) {
            __half2 p0 = __floats2half2_rn(acc[i][0], acc[i][1]);
            __half2 p1 = __floats2half2_rn(acc[i][2], acc[i][3]);
            uint2 pk = make_uint2(*(unsigned*)&p0, *(unsigned*)&p1);
            *(uint2*)&h[(size_t)grow * 64 + tx * 4] = pk;   // 8B store
        }
        float s1 = acc[i][0] * asl[tx*4+0] + acc[i][1] * asl[tx*4+1]
                 + acc[i][2] * asl[tx*4+2] + acc[i][3] * asl[tx*4+3];
        float s2 = acc[i][0] * adl[tx*4+0] + acc[i][1] * adl[tx*4+1]
                 + acc[i][2] * adl[tx*4+2] + acc[i][3] * adl[tx*4+3];
        #pragma unroll
        for (int m = 1; m < 16; m <<= 1) {
            s1 += __shfl_xor(s1, m, 64);
            s2 += __shfl_xor(s2, m, 64);
        }
        if (grow < n) wmax = fmaxf(wmax, s1);
        if (tx == 0 && grow < n) { s_src[grow] = s1; s_dst[grow] = s2; }
    }
    wmax = fmaxf(wmax, __shfl_xor(wmax, 16, 64));
    wmax = fmaxf(wmax, __shfl_xor(wmax, 32, 64));
    if ((tid & 63) == 0) wm[tid >> 6] = wmax;
    __syncthreads();
    if (tid == 0) {
        float bm = fmaxf(fmaxf(wm[0], wm[1]), fmaxf(wm[2], wm[3]));
        atomicMax(gmax_enc, enc_f(bm));
    }
}

// ---------------------------------------------------------------------------
// CSR build: count(+rank) -> scan1 -> scanApply -> atomic-free scatter
// ---------------------------------------------------------------------------
__global__ __launch_bounds__(256) void count_rank_kernel(
    const int* __restrict__ dst, int* __restrict__ counts, int* __restrict__ rank)
{
    int e = blockIdx.x * 256 + threadIdx.x;
    if (e >= N_EDGES) return;
    rank[e] = atomicAdd(&counts[dst[e]], 1);
}

__global__ __launch_bounds__(256) void scan1_kernel(
    const int* __restrict__ counts, int* __restrict__ row_off,
    int* __restrict__ bsum, int n)
{
    __shared__ int tmp[256];
    int tid = threadIdx.x;
    int i = blockIdx.x * 256 + tid;
    int v = (i < n) ? counts[i] : 0;
    tmp[tid] = v; __syncthreads();
    for (int off = 1; off < 256; off <<= 1) {
        int add = (tid >= off) ? tmp[tid - off] : 0;
        __syncthreads();
        tmp[tid] += add;
        __syncthreads();
    }
    if (i < n) row_off[i] = tmp[tid] - v;
    if (tid == 255) bsum[blockIdx.x] = tmp[255];
}

__global__ __launch_bounds__(256) void scan_apply_kernel(
    int* __restrict__ row_off, const int* __restrict__ bsum, int n, int nb)
{
    __shared__ int tmp[256];
    int tid = threadIdx.x;
    int v = (tid < nb) ? bsum[tid] : 0;
    tmp[tid] = v; __syncthreads();
    for (int off = 1; off < 256; off <<= 1) {
        int add = (tid >= off) ? tmp[tid - off] : 0;
        __syncthreads();
        tmp[tid] += add;
        __syncthreads();
    }
    int prefix = (blockIdx.x == 0) ? 0 : tmp[blockIdx.x - 1];
    int i = blockIdx.x * 256 + tid;
    if (i < n) row_off[i] += prefix;
    if (i == 0) row_off[n] = N_EDGES;
}

__global__ __launch_bounds__(256) void scatter_kernel(
    const int* __restrict__ src, const int* __restrict__ dst,
    const int* __restrict__ row_off, const int* __restrict__ rank,
    int* __restrict__ csr_src)
{
    int e = blockIdx.x * 256 + threadIdx.x;
    if (e >= N_EDGES) return;
    csr_src[row_off[dst[e]] + rank[e]] = src[e];
}

// ---------------------------------------------------------------------------
// Fused per-node attention kernel. One wave per dst node; h gathered as fp16
// (128B/row = one cache line). m = leaky(gmax + sd) is a wave-uniform upper
// bound on incoming logits (cancels exactly in softmax) -> no max pass.
// ---------------------------------------------------------------------------
template <bool RELU>
__global__ __launch_bounds__(256) void gat_node_kernel(
    const int* __restrict__ row_off, const int* __restrict__ csr_src,
    const float* __restrict__ s_src, const float* __restrict__ s_dst,
    const __half* __restrict__ h, const float* __restrict__ b,
    const unsigned* __restrict__ gmax_enc, float* __restrict__ out, int n)
{
    int row = blockIdx.x * 4 + (threadIdx.x >> 6);
    int lane = threadIdx.x & 63;
    if (row >= n) return;

    int beg = row_off[row], end = row_off[row + 1];
    int deg = end - beg;
    float sd = s_dst[row];
    float m = leaky(dec_f(*gmax_enc) + sd);
    float s_self = s_src[row];
    float hself = __half2float(h[(size_t)row * 64 + lane]);
    float wself = __expf(leaky(s_self + sd) - m);

    if (deg <= 32) {                            // ~all nodes (Poisson lambda=16)
        int mysrc = row;                        // filler: hot self row, w=0
        if (lane < deg) mysrc = csr_src[beg + lane];
        float my_s = s_src[mysrc];
        float hv[32];
        #pragma unroll
        for (int j = 0; j < 32; ++j) {
            int s = __builtin_amdgcn_readlane(mysrc, j);
            hv[j] = __half2float(h[(size_t)s * 64 + lane]);
        }
        float mylogit = (lane < deg) ? leaky(my_s + sd) : -INFINITY;
        float w64 = __expf(mylogit - m);
        float den = w64;
        #pragma unroll
        for (int off = 32; off; off >>= 1)
            den += __shfl_xor(den, off, 64);
        den += wself;

        float acc = wself * hself;
        #pragma unroll
        for (int j = 0; j < 32; ++j)
            acc += readlane_f(w64, j) * hv[j];

        float v = acc / den + b[lane];
        if (RELU) v = fmaxf(v, 0.f);
        out[(size_t)row * 64 + lane] = v;
        return;
    }

    // generic path: deg > 32 (rare)
    int   mysrc   = row;
    float mylogit = -INFINITY;
    if (lane < deg) {
        mysrc = csr_src[beg + lane];
        mylogit = leaky(s_src[mysrc] + sd);
    }
    float w64 = __expf(mylogit - m);
    float den = w64;
    #pragma unroll
    for (int off = 32; off; off >>= 1)
        den += __shfl_xor(den, off, 64);
    den += wself;

    float acc = wself * hself;
    int d0 = deg < 64 ? deg : 64;
    int nb = (d0 + 15) & ~15;
    for (int i = 0; i < nb; i += 16) {
        float hv[16];
        #pragma unroll
        for (int j = 0; j < 16; ++j) {
            int s = __builtin_amdgcn_readlane(mysrc, i + j);
            hv[j] = __half2float(h[(size_t)s * 64 + lane]);
        }
        #pragma unroll
        for (int j = 0; j < 16; ++j)
            acc += readlane_f(w64, i + j) * hv[j];
    }
    for (int e = beg + 64; e < end; ++e) {      // deg > 64 tail
        int s = csr_src[e];
        float w = __expf(leaky(s_src[s] + sd) - m);
        den += w;
        acc += w * __half2float(h[(size_t)s * 64 + lane]);
    }

    float v = acc / den + b[lane];
    if (RELU) v = fmaxf(v, 0.f);
    out[(size_t)row * 64 + lane] = v;
}

// ---------------------------------------------------------------------------
extern "C" void kernel_launch(void* const* d_in, const int* in_sizes, int n_in,
                              void* d_out, int out_size, void* d_ws, size_t ws_size,
                              hipStream_t stream) {
    const float* x   = (const float*)d_in[0];
    const int*   ei  = (const int*)d_in[1];
    const float* W1  = (const float*)d_in[2];
    const float* a1s = (const float*)d_in[3];
    const float* a1d = (const float*)d_in[4];
    const float* b1  = (const float*)d_in[5];
    const float* W2  = (const float*)d_in[6];
    const float* a2s = (const float*)d_in[7];
    const float* a2d = (const float*)d_in[8];
    const float* b2  = (const float*)d_in[9];
    float* out = (float*)d_out;

    const int* src = ei;
    const int* dst = ei + N_EDGES;

    char* p = (char*)d_ws;
    __half* h   = (__half*)p;           p += (size_t)N_NODES * 64 * 2;  // fp16 now
    float* ssrc = (float*)p;            p += (size_t)N_NODES * 4;
    float* sdst = (float*)p;            p += (size_t)N_NODES * 4;
    int* row_off = (int*)p;             p += (size_t)(N_NODES + 1) * 4;
    int* bsum    = (int*)p;             p += 256 * 4;
    unsigned* gmaxu = (unsigned*)p;     p += 2 * 4;
    int* counts  = (int*)p;             p += (size_t)N_NODES * 4;
    int* csr_src = (int*)p;             p += (size_t)N_EDGES * 4;

    int* rank = (int*)h;   // h (6.4 MB) is dead until gemm1; rank needs 3.2 MB

    dim3 blk(256);
    int gemm_blocks   = (N_NODES + 63) / 64;
    int node_blocks   = (N_NODES + 3) / 4;
    int edge_blocks_t = (N_EDGES + 255) / 256;
    int scan_blocks   = (N_NODES + 255) / 256;

    // ---- CSR build (atomic-free scatter via precomputed ranks) ----
    hipMemsetAsync(gmaxu, 0, 8 + (size_t)N_NODES * 4, stream);  // gmax slots + counts
    count_rank_kernel<<<edge_blocks_t, blk, 0, stream>>>(dst, counts, rank);
    scan1_kernel<<<scan_blocks, blk, 0, stream>>>(counts, row_off, bsum, N_NODES);
    scan_apply_kernel<<<scan_blocks, blk, 0, stream>>>(row_off, bsum, N_NODES, scan_blocks);
    scatter_kernel<<<edge_blocks_t, blk, 0, stream>>>(src, dst, row_off, rank, csr_src);

    // ---- layer 1 ----
    gat_gemm_kernel<128><<<gemm_blocks, blk, 0, stream>>>(x, W1, a1s, a1d, h, ssrc, sdst, gmaxu + 0, N_NODES);
    gat_node_kernel<true><<<node_blocks, blk, 0, stream>>>(row_off, csr_src, ssrc, sdst, h, b1, gmaxu + 0, out, N_NODES);

    // ---- layer 2 ----
    gat_gemm_kernel<64><<<gemm_blocks, blk, 0, stream>>>(out, W2, a2s, a2d, h, ssrc, sdst, gmaxu + 1, N_NODES);
    gat_node_kernel<false><<<node_blocks, blk, 0, stream>>>(row_off, csr_src, ssrc, sdst, h, b2, gmaxu + 1, out, N_NODES);
}

// Round 10
// 132.152 us; speedup vs baseline: 2.4194x; 1.2491x over previous
//
#include <hip/hip_runtime.h>
#include <hip/hip_fp16.h>

#define N_NODES 50000
#define N_EDGES 800000
#define NEG_SLOPE 0.2f
#define NBKT 196            // ceil(50000/256) buckets of 256 nodes
#define EBLK 200            // edge blocks
#define CHUNK 4000          // edges per block (EBLK*CHUNK == N_EDGES)

__device__ __forceinline__ float leaky(float x) { return x >= 0.f ? x : NEG_SLOPE * x; }
__device__ __forceinline__ float readlane_f(float v, int i) {
    return __uint_as_float(__builtin_amdgcn_readlane(__float_as_uint(v), i));
}
// order-preserving float<->uint mapping for atomicMax on mixed-sign floats
__device__ __forceinline__ unsigned enc_f(float f) {
    unsigned u = __float_as_uint(f);
    return (int)u < 0 ? ~u : (u | 0x80000000u);
}
__device__ __forceinline__ float dec_f(unsigned e) {
    return __uint_as_float((int)e < 0 ? (e & 0x7FFFFFFFu) : ~e);
}

// ---------------------------------------------------------------------------
// Register-tiled GEMM + attention scores: h(fp16) = x@W, s_src/s_dst (f32),
// gmax accumulated via one encoded atomicMax per block.
// ---------------------------------------------------------------------------
template <int K>
__global__ __launch_bounds__(256) void gat_gemm_kernel(
    const float* __restrict__ x, const float* __restrict__ W,
    const float* __restrict__ a_src, const float* __restrict__ a_dst,
    __half* __restrict__ h, float* __restrict__ s_src, float* __restrict__ s_dst,
    unsigned* __restrict__ gmax_enc, int n)
{
    constexpr int BK = 32;
    __shared__ float Wl[BK][64];
    __shared__ float xt[BK][68];
    __shared__ float asl[64], adl[64];
    __shared__ float wm[4];

    int tid = threadIdx.x;
    if (tid < 64) { asl[tid] = a_src[tid]; adl[tid] = a_dst[tid]; }
    int tx = tid & 15, ty = tid >> 4;
    int row0 = blockIdx.x * 64;

    float acc[4][4] = {};

    for (int k0 = 0; k0 < K; k0 += BK) {
        __syncthreads();
        {
            const float4* Wg = (const float4*)&W[(size_t)k0 * 64];
            float4* Ws = (float4*)&Wl[0][0];
            Ws[tid]       = Wg[tid];
            Ws[tid + 256] = Wg[tid + 256];
        }
        #pragma unroll
        for (int it = 0; it < 2; ++it) {
            int idx = tid + it * 256;
            int r = idx >> 3, kq = idx & 7;
            int grow = row0 + r;
            float4 v = (grow < n) ? *(const float4*)&x[(size_t)grow * K + k0 + kq * 4]
                                  : make_float4(0.f, 0.f, 0.f, 0.f);
            xt[kq * 4 + 0][r] = v.x;
            xt[kq * 4 + 1][r] = v.y;
            xt[kq * 4 + 2][r] = v.z;
            xt[kq * 4 + 3][r] = v.w;
        }
        __syncthreads();

        #pragma unroll
        for (int kk = 0; kk < BK; ++kk) {
            float4 wv = *(const float4*)&Wl[kk][tx * 4];
            float4 xv = *(const float4*)&xt[kk][ty * 4];
            acc[0][0] += xv.x * wv.x; acc[0][1] += xv.x * wv.y; acc[0][2] += xv.x * wv.z; acc[0][3] += xv.x * wv.w;
            acc[1][0] += xv.y * wv.x; acc[1][1] += xv.y * wv.y; acc[1][2] += xv.y * wv.z; acc[1][3] += xv.y * wv.w;
            acc[2][0] += xv.z * wv.x; acc[2][1] += xv.z * wv.y; acc[2][2] += xv.z * wv.z; acc[2][3] += xv.z * wv.w;
            acc[3][0] += xv.w * wv.x; acc[3][1] += xv.w * wv.y; acc[3][2] += xv.w * wv.z; acc[3][3] += xv.w * wv.w;
        }
    }

    float wmax = -INFINITY;
    #pragma unroll
    for (int i = 0; i < 4; ++i) {
        int grow = row0 + ty * 4 + i;
        if (grow < n) {
            __half2 p0 = __floats2half2_rn(acc[i][0], acc[i][1]);
            __half2 p1 = __floats2half2_rn(acc[i][2], acc[i][3]);
            uint2 pk = make_uint2(*(unsigned*)&p0, *(unsigned*)&p1);
            *(uint2*)&h[(size_t)grow * 64 + tx * 4] = pk;
        }
        float s1 = acc[i][0] * asl[tx*4+0] + acc[i][1] * asl[tx*4+1]
                 + acc[i][2] * asl[tx*4+2] + acc[i][3] * asl[tx*4+3];
        float s2 = acc[i][0] * adl[tx*4+0] + acc[i][1] * adl[tx*4+1]
                 + acc[i][2] * adl[tx*4+2] + acc[i][3] * adl[tx*4+3];
        #pragma unroll
        for (int m = 1; m < 16; m <<= 1) {
            s1 += __shfl_xor(s1, m, 64);
            s2 += __shfl_xor(s2, m, 64);
        }
        if (grow < n) wmax = fmaxf(wmax, s1);
        if (tx == 0 && grow < n) { s_src[grow] = s1; s_dst[grow] = s2; }
    }
    wmax = fmaxf(wmax, __shfl_xor(wmax, 16, 64));
    wmax = fmaxf(wmax, __shfl_xor(wmax, 32, 64));
    if ((tid & 63) == 0) wm[tid >> 6] = wmax;
    __syncthreads();
    if (tid == 0) {
        float bm = fmaxf(fmaxf(wm[0], wm[1]), fmaxf(wm[2], wm[3]));
        atomicMax(gmax_enc, enc_f(bm));
    }
}

// ---------------------------------------------------------------------------
// CSR build, zero global atomics (two-level counting sort; atomics in LDS).
// ---------------------------------------------------------------------------
// P1: per-block bucket histogram. Also zero-inits gmaxu (replaces memset).
__global__ __launch_bounds__(256) void p1_count(
    const int* __restrict__ dst, int* __restrict__ cnt, unsigned* __restrict__ gmaxu)
{
    __shared__ int bins[NBKT];
    int tid = threadIdx.x, b = blockIdx.x;
    if (tid < NBKT) bins[tid] = 0;
    if (b == 0 && tid >= 254) gmaxu[tid - 254] = 0;
    __syncthreads();
    int e0 = b * CHUNK;
    for (int e = e0 + tid; e < e0 + CHUNK; e += 256)
        atomicAdd(&bins[dst[e] >> 8], 1);
    __syncthreads();
    if (tid < NBKT) cnt[b * NBKT + tid] = bins[tid];
}

// P2: per-bucket column scan over the EBLK blocks (in place) + bucket totals.
__global__ __launch_bounds__(256) void p2_scan(
    int* __restrict__ cnt, int* __restrict__ btot)
{
    __shared__ int tmp[256];
    int j = blockIdx.x, tid = threadIdx.x;
    int v = (tid < EBLK) ? cnt[tid * NBKT + j] : 0;
    tmp[tid] = v; __syncthreads();
    for (int off = 1; off < 256; off <<= 1) {
        int a = (tid >= off) ? tmp[tid - off] : 0;
        __syncthreads();
        tmp[tid] += a;
        __syncthreads();
    }
    if (tid < EBLK) cnt[tid * NBKT + j] = tmp[tid] - v;   // exclusive
    if (tid == EBLK - 1) btot[j] = tmp[tid];              // bucket total
}

// P3: scatter edges into contiguous bucket regions; LDS cursors only.
// bkted[pos] = (dst&255)<<16 | src   (src < 65536 fits 16 bits)
__global__ __launch_bounds__(256) void p3_bucket(
    const int* __restrict__ src, const int* __restrict__ dst,
    const int* __restrict__ cnt, const int* __restrict__ btot,
    unsigned* __restrict__ bkted)
{
    __shared__ int tmp[256];
    __shared__ int boffL[NBKT];
    int b = blockIdx.x, tid = threadIdx.x;
    int v = (tid < NBKT) ? btot[tid] : 0;
    tmp[tid] = v; __syncthreads();
    for (int off = 1; off < 256; off <<= 1) {
        int a = (tid >= off) ? tmp[tid - off] : 0;
        __syncthreads();
        tmp[tid] += a;
        __syncthreads();
    }
    if (tid < NBKT) boffL[tid] = (tmp[tid] - v) + cnt[b * NBKT + tid]; // bucket base + my block's offset
    __syncthreads();
    int e0 = b * CHUNK;
    for (int e = e0 + tid; e < e0 + CHUNK; e += 256) {
        int d = dst[e], s = src[e];
        int pos = atomicAdd(&boffL[d >> 8], 1);
        bkted[pos] = ((unsigned)(d & 255) << 16) | (unsigned)s;
    }
}

// P4: one block per bucket; per-node count/scan/scatter in LDS; writes
// row_off and csr_src directly.
__global__ __launch_bounds__(256) void p4_csr(
    const unsigned* __restrict__ bkted, const int* __restrict__ btot,
    int* __restrict__ row_off, int* __restrict__ csr_src)
{
    __shared__ int tmp[256];
    __shared__ int cur[256];
    __shared__ int s_beg, s_end;
    int j = blockIdx.x, tid = threadIdx.x;
    int v = (tid < NBKT) ? btot[tid] : 0;
    tmp[tid] = v; __syncthreads();
    for (int off = 1; off < 256; off <<= 1) {
        int a = (tid >= off) ? tmp[tid - off] : 0;
        __syncthreads();
        tmp[tid] += a;
        __syncthreads();
    }
    if (tid == j) { s_beg = tmp[tid] - v; s_end = tmp[tid]; }
    cur[tid] = 0;
    __syncthreads();
    int beg = s_beg, end = s_end;

    // count per local node
    for (int e = beg + tid; e < end; e += 256)
        atomicAdd(&cur[bkted[e] >> 16], 1);
    __syncthreads();
    int c = cur[tid];
    tmp[tid] = c; __syncthreads();
    for (int off = 1; off < 256; off <<= 1) {
        int a = (tid >= off) ? tmp[tid - off] : 0;
        __syncthreads();
        tmp[tid] += a;
        __syncthreads();
    }
    int offx = tmp[tid] - c;                  // exclusive local offset
    int node = j * 256 + tid;
    if (node < N_NODES) row_off[node] = beg + offx;
    if (node == 0) row_off[N_NODES] = N_EDGES;
    __syncthreads();
    cur[tid] = offx;                          // reuse as cursor
    __syncthreads();
    for (int e = beg + tid; e < end; e += 256) {
        unsigned u = bkted[e];
        int pos = beg + atomicAdd(&cur[u >> 16], 1);
        csr_src[pos] = (int)(u & 0xFFFFu);
    }
}

// ---------------------------------------------------------------------------
// Fused per-node attention kernel (unchanged from R9). One wave per node;
// fp16 h gathers (128 B row = one line); global-max bound -> no max pass.
// ---------------------------------------------------------------------------
template <bool RELU>
__global__ __launch_bounds__(256) void gat_node_kernel(
    const int* __restrict__ row_off, const int* __restrict__ csr_src,
    const float* __restrict__ s_src, const float* __restrict__ s_dst,
    const __half* __restrict__ h, const float* __restrict__ b,
    const unsigned* __restrict__ gmax_enc, float* __restrict__ out, int n)
{
    int row = blockIdx.x * 4 + (threadIdx.x >> 6);
    int lane = threadIdx.x & 63;
    if (row >= n) return;

    int beg = row_off[row], end = row_off[row + 1];
    int deg = end - beg;
    float sd = s_dst[row];
    float m = leaky(dec_f(*gmax_enc) + sd);
    float s_self = s_src[row];
    float hself = __half2float(h[(size_t)row * 64 + lane]);
    float wself = __expf(leaky(s_self + sd) - m);

    if (deg <= 32) {
        int mysrc = row;
        if (lane < deg) mysrc = csr_src[beg + lane];
        float my_s = s_src[mysrc];
        float hv[32];
        #pragma unroll
        for (int j = 0; j < 32; ++j) {
            int s = __builtin_amdgcn_readlane(mysrc, j);
            hv[j] = __half2float(h[(size_t)s * 64 + lane]);
        }
        float mylogit = (lane < deg) ? leaky(my_s + sd) : -INFINITY;
        float w64 = __expf(mylogit - m);
        float den = w64;
        #pragma unroll
        for (int off = 32; off; off >>= 1)
            den += __shfl_xor(den, off, 64);
        den += wself;

        float acc = wself * hself;
        #pragma unroll
        for (int j = 0; j < 32; ++j)
            acc += readlane_f(w64, j) * hv[j];

        float v = acc / den + b[lane];
        if (RELU) v = fmaxf(v, 0.f);
        out[(size_t)row * 64 + lane] = v;
        return;
    }

    // generic path: deg > 32
    int   mysrc   = row;
    float mylogit = -INFINITY;
    if (lane < deg) {
        mysrc = csr_src[beg + lane];
        mylogit = leaky(s_src[mysrc] + sd);
    }
    float w64 = __expf(mylogit - m);
    float den = w64;
    #pragma unroll
    for (int off = 32; off; off >>= 1)
        den += __shfl_xor(den, off, 64);
    den += wself;

    float acc = wself * hself;
    int d0 = deg < 64 ? deg : 64;
    int nb = (d0 + 15) & ~15;
    for (int i = 0; i < nb; i += 16) {
        float hv[16];
        #pragma unroll
        for (int j = 0; j < 16; ++j) {
            int s = __builtin_amdgcn_readlane(mysrc, i + j);
            hv[j] = __half2float(h[(size_t)s * 64 + lane]);
        }
        #pragma unroll
        for (int j = 0; j < 16; ++j)
            acc += readlane_f(w64, i + j) * hv[j];
    }
    for (int e = beg + 64; e < end; ++e) {
        int s = csr_src[e];
        float w = __expf(leaky(s_src[s] + sd) - m);
        den += w;
        acc += w * __half2float(h[(size_t)s * 64 + lane]);
    }

    float v = acc / den + b[lane];
    if (RELU) v = fmaxf(v, 0.f);
    out[(size_t)row * 64 + lane] = v;
}

// ---------------------------------------------------------------------------
extern "C" void kernel_launch(void* const* d_in, const int* in_sizes, int n_in,
                              void* d_out, int out_size, void* d_ws, size_t ws_size,
                              hipStream_t stream) {
    const float* x   = (const float*)d_in[0];
    const int*   ei  = (const int*)d_in[1];
    const float* W1  = (const float*)d_in[2];
    const float* a1s = (const float*)d_in[3];
    const float* a1d = (const float*)d_in[4];
    const float* b1  = (const float*)d_in[5];
    const float* W2  = (const float*)d_in[6];
    const float* a2s = (const float*)d_in[7];
    const float* a2d = (const float*)d_in[8];
    const float* b2  = (const float*)d_in[9];
    float* out = (float*)d_out;

    const int* src = ei;
    const int* dst = ei + N_EDGES;

    char* p = (char*)d_ws;
    __half* h   = (__half*)p;           p += (size_t)N_NODES * 64 * 2;
    float* ssrc = (float*)p;            p += (size_t)N_NODES * 4;
    float* sdst = (float*)p;            p += (size_t)N_NODES * 4;
    int* row_off = (int*)p;             p += (size_t)(N_NODES + 1) * 4;
    unsigned* gmaxu = (unsigned*)p;     p += 4 * 4;
    int* csr_src = (int*)p;             p += (size_t)N_EDGES * 4;
    int* cnt     = (int*)p;             p += (size_t)EBLK * NBKT * 4;
    int* btot    = (int*)p;             p += (size_t)NBKT * 4;

    unsigned* bkted = (unsigned*)h;  // h (6.4 MB) dead until gemm1; bkted = 3.2 MB

    dim3 blk(256);
    int gemm_blocks = (N_NODES + 63) / 64;
    int node_blocks = (N_NODES + 3) / 4;

    // ---- CSR build: zero global atomics ----
    p1_count<<<EBLK, blk, 0, stream>>>(dst, cnt, gmaxu);
    p2_scan<<<NBKT, blk, 0, stream>>>(cnt, btot);
    p3_bucket<<<EBLK, blk, 0, stream>>>(src, dst, cnt, btot, bkted);
    p4_csr<<<NBKT, blk, 0, stream>>>(bkted, btot, row_off, csr_src);

    // ---- layer 1 ----
    gat_gemm_kernel<128><<<gemm_blocks, blk, 0, stream>>>(x, W1, a1s, a1d, h, ssrc, sdst, gmaxu + 0, N_NODES);
    gat_node_kernel<true><<<node_blocks, blk, 0, stream>>>(row_off, csr_src, ssrc, sdst, h, b1, gmaxu + 0, out, N_NODES);

    // ---- layer 2 ----
    gat_gemm_kernel<64><<<gemm_blocks, blk, 0, stream>>>(out, W2, a2s, a2d, h, ssrc, sdst, gmaxu + 1, N_NODES);
    gat_node_kernel<false><<<node_blocks, blk, 0, stream>>>(row_off, csr_src, ssrc, sdst, h, b2, gmaxu + 1, out, N_NODES);
}